// Round 11
// baseline (103.900 us; speedup 1.0000x reference)
//
#include <hip/hip_runtime.h>

#define HW   4096
#define Hh   64
#define Ww   64
#define NB   27
#define EPSBN 1e-5f

typedef _Float16 f16x8 __attribute__((ext_vector_type(8)));
typedef _Float16 f16x4 __attribute__((ext_vector_type(4)));
typedef _Float16 f16x2 __attribute__((ext_vector_type(2)));
typedef float    f32x4 __attribute__((ext_vector_type(4)));

// async global->LDS, 16B per lane; LDS dest = wave-uniform base + lane*16
__device__ __forceinline__ void gld_lds16(const void* g, void* l) {
    __builtin_amdgcn_global_load_lds(
        (const __attribute__((address_space(1))) unsigned int*)g,
        (__attribute__((address_space(3))) unsigned int*)l, 16, 0, 0);
}

// ---------------------------------------------------------------------------
// prep: weights f32 -> f16 (x consumed directly by stage-1 GEMM).
// ---------------------------------------------------------------------------
__global__ __launch_bounds__(256)
void prep_kernel(const float* s0, const float* s1, const float* s2,
                 const float* s3, const float* s4, const float* s5,
                 _Float16* d0, _Float16* d1, _Float16* d2,
                 _Float16* d3, _Float16* d4, _Float16* d5)
{
    const int bid = blockIdx.x;
    const int j  = bid >> 6;
    const int bx = bid & 63;
    const float* s = j==0?s0: j==1?s1: j==2?s2: j==3?s3: j==4?s4: s5;
    _Float16*  d = j==0?d0: j==1?d1: j==2?d2: j==3?d3: j==4?d4: d5;
    const int  n = (j==3 || j==4) ? 65536 : 131072;
    const int  i = (bx * 256 + threadIdx.x) * 8;
    if (i < n) {
        f16x8 h;
        #pragma unroll
        for (int k = 0; k < 8; ++k) h[k] = (_Float16)s[i + k];
        *(f16x8*)(d + i) = h;
    }
}

// ---------------------------------------------------------------------------
// Single-buffered MFMA GEMM, occupancy-first (m97-classic 2-barrier loop):
// 64x128 tile (MxN), BK=64, 4 waves x (32x64 = 2x4 16x16x32 f16 frags).
// LDS = 8KB(A) + 16KB(B) = 24KB -> 5-6 blocks/CU (TLP hides load latency;
// R10's 64KB dbuf gave 13.5% occupancy and stalled at MfmaUtil 10%).
// B source (block-uniform): Jin f16 (p,c) via global_load_lds, or Jxf f32
// (b,c,p) reg-staged (32 coalesced dword loads, one waitcnt, cvt+swizzled
// ds_write). XOR swizzle (byte col ^= (row&7)<<4) on write and read sides.
// Locality grid: bid -> xcd=bid&7, nb=xcd*16+jj/nmbTot, mb=jj%nmbTot so all
// mb-blocks sharing a B-chunk run consecutively on one XCD.
// mode: 0 = f16 out (p,c);  2 = f32 out (b,c,p)
// ---------------------------------------------------------------------------
struct GJob {
    const _Float16* in;   // (16384, K) f16, or null
    const float*    xf;   // (b,c,p) f32, or null
    const _Float16* w;    // (O, K) f16
    const float* b; const float* g; const float* be; const float* m; const float* v;
    _Float16* oh;
    float*    of;
};

__global__ __launch_bounds__(256)
void gemm64(GJob J0, GJob J1, GJob J2, int nmb0, int nmb01, int nmbTot,
            int K, int JO, int mode)
{
    __shared__ _Float16 As[64 * 64];     // 8 KB
    __shared__ _Float16 Bs[128 * 64];    // 16 KB

    const int tid  = threadIdx.x;
    const int lane = tid & 63;
    const int w    = tid >> 6;
    const int lr   = lane & 15;
    const int lg   = lane >> 4;
    const int wm   = w & 1;              // M half (32 rows)
    const int wn   = w >> 1;             // N half (64 px)

    const int bid = blockIdx.x;
    const int xcd = bid & 7;
    const int jj  = bid >> 3;
    const int nb  = xcd * 16 + jj / nmbTot;
    const int mb  = jj % nmbTot;

    const bool i0 = mb < nmb0;
    const bool i1 = !i0 && mb < nmb01;
#define SELJ(f) (i0 ? J0.f : (i1 ? J1.f : J2.f))
    const _Float16* Jin = SELJ(in);
    const float*    Jxf = SELJ(xf);
    const _Float16* Jw  = SELJ(w);
    const float* Jb  = SELJ(b);
    const float* Jg  = SELJ(g);
    const float* Jbe = SELJ(be);
    const float* Jm  = SELJ(m);
    const float* Jv  = SELJ(v);
    _Float16* Joh = SELJ(oh);
    float*    Jof = SELJ(of);
#undef SELJ
    const int obase = (mb - (i0 ? 0 : (i1 ? nmb0 : nmb01))) * 64;

    // staging source cols pre-swizzled (rule #21); base rows are mult-of-8 so
    // the XOR key is (lane>>3) for both A and B
    const int scol = (((lane & 7) ^ (lane >> 3)) << 3);
    const int rowA = w * 16 + (lane >> 3);
    const _Float16* aSrc = Jw + (size_t)(obase + rowA) * K + scol;
    const int rowB = w * 32 + (lane >> 3);
    const _Float16* bSrc = Jin ? (Jin + (size_t)(nb * 128 + rowB) * K + scol) : nullptr;

    // f32-direct B staging: thread = (pixel row 0..127, channel half 0/1)
    const int xrow = tid & 127;
    const int chq  = tid >> 7;
    const float* xbase = nullptr;
    if (Jxf) {
        const int bb = nb >> 5;
        const int pp = (nb & 31) * 128 + xrow;
        xbase = Jxf + (size_t)bb * 512 * HW + pp;    // + c*HW per channel
    }
    const int bxorw = (xrow & 7) << 4;

    f32x4 acc[2][4] = {};
    const int nr = K >> 6;

    for (int rd = 0; rd < nr; ++rd) {
        const int kb = rd * 64;
        __syncthreads();                             // prev compute done
        gld_lds16(aSrc + kb,                  (char*)As + w * 2048);
        gld_lds16(aSrc + (size_t)8 * K + kb,  (char*)As + w * 2048 + 1024);
        if (Jxf) {
            float fr[32];                            // issue all 32, 1 waitcnt
            #pragma unroll
            for (int g2 = 0; g2 < 4; ++g2)
                #pragma unroll
                for (int i2 = 0; i2 < 8; ++i2)
                    fr[g2 * 8 + i2] = xbase[(size_t)(kb + chq * 32 + g2 * 8 + i2) * HW];
            #pragma unroll
            for (int g2 = 0; g2 < 4; ++g2) {
                f16x8 hv;
                #pragma unroll
                for (int i2 = 0; i2 < 8; ++i2) hv[i2] = (_Float16)fr[g2 * 8 + i2];
                *(f16x8*)((char*)Bs + xrow * 128 + ((chq * 64 + g2 * 16) ^ bxorw)) = hv;
            }
        } else {
            #pragma unroll
            for (int j2 = 0; j2 < 4; ++j2)
                gld_lds16(bSrc + (size_t)j2 * 8 * K + kb, (char*)Bs + w * 4096 + j2 * 1024);
        }
        __syncthreads();                             // drains vm+lgkm

        #pragma unroll
        for (int ks = 0; ks < 2; ++ks) {
            const int colx = (ks * 64 + lg * 16) ^ ((lr & 7) << 4);
            f16x8 afr[2], bfr[4];
            afr[0] = *(const f16x8*)((const char*)As + (wm * 32 + lr) * 128 + colx);
            afr[1] = *(const f16x8*)((const char*)As + (wm * 32 + 16 + lr) * 128 + colx);
            #pragma unroll
            for (int t = 0; t < 4; ++t)
                bfr[t] = *(const f16x8*)((const char*)Bs + (wn * 64 + t * 16 + lr) * 128 + colx);
            #pragma unroll
            for (int ai = 0; ai < 2; ++ai)
                #pragma unroll
                for (int bj = 0; bj < 4; ++bj)
                    acc[ai][bj] = __builtin_amdgcn_mfma_f32_16x16x32_f16(
                        afr[ai], bfr[bj], acc[ai][bj], 0, 0, 0);
        }
    }

    const int relu = (Jg != nullptr);
    #pragma unroll
    for (int ai = 0; ai < 2; ++ai) {
        const int o4 = obase + wm * 32 + ai * 16 + lg * 4;
        float sc[4], of_[4];
        #pragma unroll
        for (int r = 0; r < 4; ++r) {
            const int o = o4 + r;
            if (Jg) { float s = Jg[o] * rsqrtf(Jv[o] + EPSBN); sc[r] = s; of_[r] = fmaf(Jb[o] - Jm[o], s, Jbe[o]); }
            else    { sc[r] = 1.f; of_[r] = Jb[o]; }
        }
        #pragma unroll
        for (int bj = 0; bj < 4; ++bj) {
            const int pg = nb * 128 + wn * 64 + bj * 16 + lr;
            float vv[4];
            #pragma unroll
            for (int r = 0; r < 4; ++r) {
                float t = fmaf(acc[ai][bj][r], sc[r], of_[r]);
                vv[r] = relu ? fmaxf(t, 0.f) : t;
            }
            if (mode == 0) {
                f16x4 hh;
                #pragma unroll
                for (int r = 0; r < 4; ++r) hh[r] = (_Float16)vv[r];
                *(f16x4*)(Joh + (size_t)pg * JO + o4) = hh;
            } else {
                #pragma unroll
                for (int r = 0; r < 4; ++r)
                    Jof[((size_t)(pg >> 12) * JO + o4 + r) * HW + (pg & 4095)] = vv[r];
            }
        }
    }
}

// ---------------------------------------------------------------------------
// Fused attention: sim + softmax + PV, all buffers (b,p,256) f16.
// Thread = (pixel, 8-ch slot); 32 consecutive lanes read one 512B neighbor
// row coalesced. fdot2 sim partials; shfl_xor reduce over 32 slot-lanes;
// in-register softmax; OOB zeroed via valf (matches zero-padded unfold).
// ---------------------------------------------------------------------------
__global__ __launch_bounds__(256)
void attn_fused(const _Float16* __restrict__ keyT, const _Float16* __restrict__ qryT,
                const _Float16* __restrict__ valT, _Float16* __restrict__ ctxT)
{
    const int tid  = threadIdx.x;
    const int slot = tid & 31;
    const int b    = blockIdx.y;
    const int p    = blockIdx.x * 8 + (tid >> 5);
    const int y    = p >> 6;
    const int xc   = p & 63;

    int   idx[NB];
    float valf[NB];
    #pragma unroll
    for (int n = 0; n < NB; ++n) {
        const int d  = (n < 9) ? 1 : (n < 18 ? 2 : 4);
        const int i  = (n / 3) % 3 - 1;
        const int j  = n % 3 - 1;
        const int yy = y + i * d, xx = xc + j * d;
        const bool ok = ((unsigned)yy < (unsigned)Hh) && ((unsigned)xx < (unsigned)Ww);
        idx[n]  = min(max(yy, 0), Hh - 1) * Ww + min(max(xx, 0), Ww - 1);
        valf[n] = ok ? 1.f : 0.f;
    }

    const size_t base = (size_t)b * HW * 256 + slot * 8;
    const f16x8 q8 = *(const f16x8*)(qryT + base + (size_t)p * 256);

    f16x2 qp[4];
    qp[0] = __builtin_shufflevector(q8, q8, 0, 1);
    qp[1] = __builtin_shufflevector(q8, q8, 2, 3);
    qp[2] = __builtin_shufflevector(q8, q8, 4, 5);
    qp[3] = __builtin_shufflevector(q8, q8, 6, 7);

    float sim[NB];
    #pragma unroll
    for (int n = 0; n < NB; ++n) {
        const f16x8 k8 = *(const f16x8*)(keyT + base + (size_t)idx[n] * 256);
        float s = 0.f;
        s = __builtin_amdgcn_fdot2(__builtin_shufflevector(k8, k8, 0, 1), qp[0], s, false);
        s = __builtin_amdgcn_fdot2(__builtin_shufflevector(k8, k8, 2, 3), qp[1], s, false);
        s = __builtin_amdgcn_fdot2(__builtin_shufflevector(k8, k8, 4, 5), qp[2], s, false);
        s = __builtin_amdgcn_fdot2(__builtin_shufflevector(k8, k8, 6, 7), qp[3], s, false);
        sim[n] = s;
    }

    #pragma unroll
    for (int n = 0; n < NB; ++n) {
        float s = sim[n];
        s += __shfl_xor(s, 1);
        s += __shfl_xor(s, 2);
        s += __shfl_xor(s, 4);
        s += __shfl_xor(s, 8);
        s += __shfl_xor(s, 16);
        sim[n] = s * valf[n];
    }

    float mx = sim[0];
    #pragma unroll
    for (int n = 1; n < NB; ++n) mx = fmaxf(mx, sim[n]);
    float sum = 0.f;
    #pragma unroll
    for (int n = 0; n < NB; ++n) { sim[n] = __expf(sim[n] - mx); sum += sim[n]; }
    const float inv = 1.f / sum;
    #pragma unroll
    for (int n = 0; n < NB; ++n) sim[n] = sim[n] * inv * valf[n];

    float acc[8];
    #pragma unroll
    for (int i = 0; i < 8; ++i) acc[i] = 0.f;
    #pragma unroll
    for (int n = 0; n < NB; ++n) {
        const f16x8 v8 = *(const f16x8*)(valT + base + (size_t)idx[n] * 256);
        const float w = sim[n];
        #pragma unroll
        for (int i = 0; i < 8; ++i) acc[i] = fmaf(w, (float)v8[i], acc[i]);
    }

    f16x8 h;
    #pragma unroll
    for (int i = 0; i < 8; ++i) h[i] = (_Float16)acc[i];
    *(f16x8*)(ctxT + base + (size_t)p * 256) = h;
}

extern "C" void kernel_launch(void* const* d_in, const int* in_sizes, int n_in,
                              void* d_out, int out_size, void* d_ws, size_t ws_size,
                              hipStream_t stream)
{
    (void)in_sizes; (void)n_in; (void)out_size; (void)ws_size;
    const float* x     = (const float*)d_in[0];
    const float* k1_w  = (const float*)d_in[1];
    const float* k1_b  = (const float*)d_in[2];
    const float* k1_g  = (const float*)d_in[3];
    const float* k1_be = (const float*)d_in[4];
    const float* k1_m  = (const float*)d_in[5];
    const float* k1_v  = (const float*)d_in[6];
    const float* k2_w  = (const float*)d_in[7];
    const float* k2_b  = (const float*)d_in[8];
    const float* k2_g  = (const float*)d_in[9];
    const float* k2_be = (const float*)d_in[10];
    const float* k2_m  = (const float*)d_in[11];
    const float* k2_v  = (const float*)d_in[12];
    const float* q1_w  = (const float*)d_in[13];
    const float* q1_b  = (const float*)d_in[14];
    const float* q1_g  = (const float*)d_in[15];
    const float* q1_be = (const float*)d_in[16];
    const float* q1_m  = (const float*)d_in[17];
    const float* q1_v  = (const float*)d_in[18];
    const float* q2_w  = (const float*)d_in[19];
    const float* q2_b  = (const float*)d_in[20];
    const float* q2_g  = (const float*)d_in[21];
    const float* q2_be = (const float*)d_in[22];
    const float* q2_m  = (const float*)d_in[23];
    const float* q2_v  = (const float*)d_in[24];
    const float* v_w   = (const float*)d_in[25];
    const float* v_b   = (const float*)d_in[26];
    const float* w_w   = (const float*)d_in[27];
    const float* w_b   = (const float*)d_in[28];

    _Float16* hw = (_Float16*)d_ws;
    const size_t SH = (size_t)4 * HW * 256;
    _Float16* wv_h  = hw;
    _Float16* wk1_h = wv_h  + 131072;
    _Float16* wq1_h = wk1_h + 131072;
    _Float16* wk2_h = wq1_h + 131072;
    _Float16* wq2_h = wk2_h + 65536;
    _Float16* ww_h  = wq2_h + 65536;
    _Float16* k1T   = ww_h  + 131072;
    _Float16* q1T   = k1T + SH;
    _Float16* valT  = q1T + SH;
    _Float16* ctxT  = valT + SH;
    _Float16* keyPC = ctxT + SH;
    _Float16* qryPC = keyPC + SH;

    prep_kernel<<<384, 256, 0, stream>>>(v_w, k1_w, q1_w, k2_w, q2_w, w_w,
                                         wv_h, wk1_h, wq1_h, wk2_h, wq2_h, ww_h);

    GJob jv  = { nullptr, x, wv_h,  v_b,  nullptr, nullptr, nullptr, nullptr, valT,  nullptr };
    GJob jk1 = { nullptr, x, wk1_h, k1_b, k1_g, k1_be, k1_m, k1_v,            k1T,   nullptr };
    GJob jq1 = { nullptr, x, wq1_h, q1_b, q1_g, q1_be, q1_m, q1_v,            q1T,   nullptr };
    GJob jk2 = { k1T, nullptr, wk2_h, k2_b, k2_g, k2_be, k2_m, k2_v,          keyPC, nullptr };
    GJob jq2 = { q1T, nullptr, wq2_h, q2_b, q2_g, q2_be, q2_m, q2_v,          qryPC, nullptr };
    GJob jw  = { ctxT, nullptr, ww_h, w_b,  nullptr, nullptr, nullptr, nullptr, nullptr, (float*)d_out };

    // stage 1: v | k1 | q1 (4 mb each, 64 rows/mb), K=512, B = f32 x direct
    gemm64<<<1536, 256, 0, stream>>>(jv, jk1, jq1, 4, 8, 12, 512, 256, 0);
    // stage 2: k2 | q2 (4 mb each), K=256, out f16 (p,c)
    gemm64<<<1024, 256, 0, stream>>>(jk2, jq2, jq2, 4, 8, 8, 256, 256, 0);
    // stage 3: fused sim+softmax+PV -> ctxT (p,c) f16
    attn_fused<<<dim3(512, 4), 256, 0, stream>>>(keyPC, qryPC, valT, ctxT);
    // stage 4: final conv (8 mb), K=256, out f32 (b,c,p) -> d_out
    gemm64<<<1024, 256, 0, stream>>>(jw, jw, jw, 8, 8, 8, 256, 512, 2);
}

// Round 12
// 86.908 us; speedup vs baseline: 1.1955x; 1.1955x over previous
//
#include <hip/hip_runtime.h>

#define HW   4096
#define Hh   64
#define Ww   64
#define NB   27
#define EPSBN 1e-5f

typedef _Float16 f16x8 __attribute__((ext_vector_type(8)));
typedef _Float16 f16x4 __attribute__((ext_vector_type(4)));
typedef _Float16 f16x2 __attribute__((ext_vector_type(2)));
typedef float    f32x4 __attribute__((ext_vector_type(4)));

// async global->LDS, 16B per lane; LDS dest = wave-uniform base + lane*16
__device__ __forceinline__ void gld_lds16(const void* g, void* l) {
    __builtin_amdgcn_global_load_lds(
        (const __attribute__((address_space(1))) unsigned int*)g,
        (__attribute__((address_space(3))) unsigned int*)l, 16, 0, 0);
}

// ---------------------------------------------------------------------------
// prep: weights f32 -> f16 (x consumed directly by stage-1 GEMM).
// ---------------------------------------------------------------------------
__global__ __launch_bounds__(256)
void prep_kernel(const float* s0, const float* s1, const float* s2,
                 const float* s3, const float* s4, const float* s5,
                 _Float16* d0, _Float16* d1, _Float16* d2,
                 _Float16* d3, _Float16* d4, _Float16* d5)
{
    const int bid = blockIdx.x;
    const int j  = bid >> 6;
    const int bx = bid & 63;
    const float* s = j==0?s0: j==1?s1: j==2?s2: j==3?s3: j==4?s4: s5;
    _Float16*  d = j==0?d0: j==1?d1: j==2?d2: j==3?d3: j==4?d4: d5;
    const int  n = (j==3 || j==4) ? 65536 : 131072;
    const int  i = (bx * 256 + threadIdx.x) * 8;
    if (i < n) {
        f16x8 h;
        #pragma unroll
        for (int k = 0; k < 8; ++k) h[k] = (_Float16)s[i + k];
        *(f16x8*)(d + i) = h;
    }
}

// ---------------------------------------------------------------------------
// Shared-B fused MFMA GEMM. Key idea (R11 post-mortem): MFMA duty was pinned
// at ~10% because each K-tile paid a full staging drain for only 16 MFMAs.
// Here nA A-tiles (64 rows each) share ONE staged B tile (128 px x 64 ch):
//   stage 1: nA=3 = jobs {v,k1,q1} (same B = x!), B reg-staged from f32 x
//            (T14: next tile's 16 loads issued under the MFMA cluster)
//   stage 2: nA=2 = two 64-row chunks of one job (k2 or q2 by u>>1)
//   stage 4: nA=2 = two 64-row chunks of the final conv
// Block = 512 thr = 8 waves (wm=quarter of 16 rows, wn=half of 64 px); each
// wave: nA x (16 rows x 64 px) = nA*4 frags, nA*8 MFMA per K-tile.
// LDS 40KB (A nA*8KB + B 16KB); XOR swizzle (byte ^= (row&7)<<4) write+read.
// All job fields selected as block-uniform VALUES (R3 scratch lesson).
// mode: 0 = f16 out (p,c);  2 = f32 out (b,c,p)
// ---------------------------------------------------------------------------
struct GJob {
    const _Float16* in;   // (16384, K) f16, or null
    const float*    xf;   // (b,c,p) f32, or null
    const _Float16* w;    // (O, K) f16
    const float* b; const float* g; const float* be; const float* m; const float* v;
    _Float16* oh;
    float*    of;
};

__global__ __launch_bounds__(512)
void gemm_f(GJob J0, GJob J1, GJob J2, int stage, int K, int JO, int mode)
{
    __shared__ _Float16 As[3 * 64 * 64];   // 24 KB (slot s at s*8192 bytes)
    __shared__ _Float16 Bs[128 * 64];      // 16 KB

    const int tid  = threadIdx.x;
    const int lane = tid & 63;
    const int w8   = tid >> 6;            // wave 0..7
    const int lr   = lane & 15;
    const int lg   = lane >> 4;
    const int wm   = w8 & 3;              // 16-row quarter of each A tile
    const int wn   = w8 >> 2;             // 64-px half of B tile

    const int bid = blockIdx.x;           // 512 blocks
    const int xcd = bid & 7;
    const int jj  = bid >> 3;
    const int nb  = xcd * 16 + (jj >> 2); // pixel chunk 0..127 (XCD-local)
    const int u   = jj & 3;

    const int nA = (stage == 1) ? 3 : 2;
    int js0, js1, js2, ob0, ob1, ob2;
    if (stage == 1)      { js0 = 0; js1 = 1; js2 = 2; ob0 = ob1 = ob2 = u * 64; }
    else if (stage == 2) { js0 = js1 = js2 = (u >> 1); ob0 = (u & 1) * 128; ob1 = ob0 + 64; ob2 = ob1; }
    else                 { js0 = js1 = js2 = 0; ob0 = u * 128; ob1 = ob0 + 64; ob2 = ob1; }

#define JSEL(js, f) ((js) == 0 ? J0.f : ((js) == 1 ? J1.f : J2.f))
    const _Float16* w0 = JSEL(js0, w);
    const _Float16* w1 = JSEL(js1, w);
    const _Float16* w2 = JSEL(js2, w);
    const float* b0 = JSEL(js0, b); const float* g0 = JSEL(js0, g);
    const float* be0 = JSEL(js0, be); const float* m0 = JSEL(js0, m); const float* v0 = JSEL(js0, v);
    const float* b1 = JSEL(js1, b); const float* g1 = JSEL(js1, g);
    const float* be1 = JSEL(js1, be); const float* m1 = JSEL(js1, m); const float* v1 = JSEL(js1, v);
    const float* b2 = JSEL(js2, b); const float* g2 = JSEL(js2, g);
    const float* be2 = JSEL(js2, be); const float* m2 = JSEL(js2, m); const float* v2 = JSEL(js2, v);
    _Float16* oh0 = JSEL(js0, oh); float* of0 = JSEL(js0, of);
    _Float16* oh1 = JSEL(js1, oh); float* of1 = JSEL(js1, of);
    _Float16* oh2 = JSEL(js2, oh); float* of2 = JSEL(js2, of);
    const _Float16* bIn = JSEL(js0, in);
    const float*    bXf = JSEL(js0, xf);
#undef JSEL

    // staging source cols pre-swizzled (rule #21); row bases are mult-of-8
    const int scol = (((lane & 7) ^ (lane >> 3)) << 3);
    const int rowA = w8 * 8 + (lane >> 3);        // 8 waves cover 64 rows
    const _Float16* aS0 = w0 + (size_t)(ob0 + rowA) * K + scol;
    const _Float16* aS1 = w1 + (size_t)(ob1 + rowA) * K + scol;
    const _Float16* aS2 = w2 + (size_t)(ob2 + rowA) * K + scol;

    const int rowB = w8 * 16 + (lane >> 3);       // f16-B: 8 waves x 2KB
    const _Float16* bS = bIn ? (bIn + (size_t)(nb * 128 + rowB) * K + scol) : nullptr;

    // f32-direct B staging: thread = (pixel row 0..127, 16-ch quarter)
    const int xrow  = tid & 127;
    const int chq   = tid >> 7;                   // 0..3
    const int pgS   = nb * 128 + xrow;
    const float* xbase = bXf ? (bXf + ((size_t)(pgS >> 12) * 512) * HW + (pgS & 4095)) : nullptr;
    const int bxorw = (xrow & 7) << 4;
    const bool f32B = (bXf != nullptr);

    float fr[16];
    auto ISSUE_BX = [&](int rd) {                 // 16 coalesced f32 loads
        const int cb = rd * 64 + chq * 16;
        #pragma unroll
        for (int i2 = 0; i2 < 16; ++i2)
            fr[i2] = xbase[(size_t)(cb + i2) * HW];
    };
    auto WRITE_BX = [&]() {                       // cvt + swizzled ds_write
        #pragma unroll
        for (int g4 = 0; g4 < 2; ++g4) {
            f16x8 hv;
            #pragma unroll
            for (int i2 = 0; i2 < 8; ++i2) hv[i2] = (_Float16)fr[g4 * 8 + i2];
            *(f16x8*)((char*)Bs + xrow * 128 + ((chq * 32 + g4 * 16) ^ bxorw)) = hv;
        }
    };

    f32x4 acc0[4] = {}, acc1[4] = {}, acc2[4] = {};
    const int nr = K >> 6;

    if (f32B) ISSUE_BX(0);

    for (int rd = 0; rd < nr; ++rd) {
        const int kb = rd * 64;
        __syncthreads();                          // prev compute done
        if (f32B) {
            WRITE_BX();                           // tile rd's B (loads done)
        } else {
            gld_lds16(bS + kb,                 (char*)Bs + w8 * 2048);
            gld_lds16(bS + (size_t)8 * K + kb, (char*)Bs + w8 * 2048 + 1024);
        }
        gld_lds16(aS0 + kb, (char*)As + w8 * 1024);
        gld_lds16(aS1 + kb, (char*)As + 8192 + w8 * 1024);
        if (nA > 2) gld_lds16(aS2 + kb, (char*)As + 16384 + w8 * 1024);
        __syncthreads();                          // drain vm+lgkm
        if (f32B && rd + 1 < nr) ISSUE_BX(rd + 1);  // fly under MFMAs

        #pragma unroll
        for (int ks = 0; ks < 2; ++ks) {
            const int colx = (ks * 64 + lg * 16) ^ ((lr & 7) << 4);
            const int arow = (wm * 16 + lr) * 128 + colx;
            f16x8 bfr[4];
            #pragma unroll
            for (int t = 0; t < 4; ++t)
                bfr[t] = *(const f16x8*)((const char*)Bs + (wn * 64 + t * 16 + lr) * 128 + colx);
            const f16x8 af0 = *(const f16x8*)((const char*)As + arow);
            const f16x8 af1 = *(const f16x8*)((const char*)As + 8192 + arow);
            #pragma unroll
            for (int bj = 0; bj < 4; ++bj)
                acc0[bj] = __builtin_amdgcn_mfma_f32_16x16x32_f16(af0, bfr[bj], acc0[bj], 0, 0, 0);
            #pragma unroll
            for (int bj = 0; bj < 4; ++bj)
                acc1[bj] = __builtin_amdgcn_mfma_f32_16x16x32_f16(af1, bfr[bj], acc1[bj], 0, 0, 0);
            if (nA > 2) {
                const f16x8 af2 = *(const f16x8*)((const char*)As + 16384 + arow);
                #pragma unroll
                for (int bj = 0; bj < 4; ++bj)
                    acc2[bj] = __builtin_amdgcn_mfma_f32_16x16x32_f16(af2, bfr[bj], acc2[bj], 0, 0, 0);
            }
        }
    }

    // epilogue per slot (BN fold + optional ReLU + store)
#define EPI(accS, obS, bS_, gS, beS, mS, vS, ohS, ofS) do {                      \
        const int o4 = (obS) + wm * 16 + lg * 4;                                 \
        float sc[4], off[4];                                                     \
        _Pragma("unroll")                                                        \
        for (int r = 0; r < 4; ++r) {                                            \
            const int o = o4 + r;                                                \
            if (gS) { float s = (gS)[o] * rsqrtf((vS)[o] + EPSBN);               \
                      sc[r] = s; off[r] = fmaf((bS_)[o] - (mS)[o], s, (beS)[o]); }\
            else    { sc[r] = 1.f; off[r] = (bS_)[o]; }                          \
        }                                                                        \
        _Pragma("unroll")                                                        \
        for (int bj = 0; bj < 4; ++bj) {                                         \
            const int pg = nb * 128 + wn * 64 + bj * 16 + lr;                    \
            float vv[4];                                                         \
            _Pragma("unroll")                                                    \
            for (int r = 0; r < 4; ++r) {                                        \
                float t = fmaf(accS[bj][r], sc[r], off[r]);                      \
                vv[r] = (gS) ? fmaxf(t, 0.f) : t;                                \
            }                                                                    \
            if (mode == 0) {                                                     \
                f16x4 hh;                                                        \
                _Pragma("unroll")                                                \
                for (int r = 0; r < 4; ++r) hh[r] = (_Float16)vv[r];             \
                *(f16x4*)((ohS) + (size_t)pg * JO + o4) = hh;                    \
            } else {                                                             \
                _Pragma("unroll")                                                \
                for (int r = 0; r < 4; ++r)                                      \
                    (ofS)[((size_t)(pg >> 12) * JO + o4 + r) * HW + (pg & 4095)] = vv[r]; \
            }                                                                    \
        }                                                                        \
    } while (0)

    EPI(acc0, ob0, b0, g0, be0, m0, v0, oh0, of0);
    EPI(acc1, ob1, b1, g1, be1, m1, v1, oh1, of1);
    if (nA > 2) EPI(acc2, ob2, b2, g2, be2, m2, v2, oh2, of2);
#undef EPI
}

// ---------------------------------------------------------------------------
// Fused attention: sim + softmax + PV, all buffers (b,p,256) f16.
// Thread = (pixel, 8-ch slot); 32 consecutive lanes read one 512B neighbor
// row coalesced. fdot2 sim partials; shfl_xor reduce over 32 slot-lanes;
// in-register softmax; OOB zeroed via valf (matches zero-padded unfold).
// ---------------------------------------------------------------------------
__global__ __launch_bounds__(256)
void attn_fused(const _Float16* __restrict__ keyT, const _Float16* __restrict__ qryT,
                const _Float16* __restrict__ valT, _Float16* __restrict__ ctxT)
{
    const int tid  = threadIdx.x;
    const int slot = tid & 31;
    const int b    = blockIdx.y;
    const int p    = blockIdx.x * 8 + (tid >> 5);
    const int y    = p >> 6;
    const int xc   = p & 63;

    int   idx[NB];
    float valf[NB];
    #pragma unroll
    for (int n = 0; n < NB; ++n) {
        const int d  = (n < 9) ? 1 : (n < 18 ? 2 : 4);
        const int i  = (n / 3) % 3 - 1;
        const int j  = n % 3 - 1;
        const int yy = y + i * d, xx = xc + j * d;
        const bool ok = ((unsigned)yy < (unsigned)Hh) && ((unsigned)xx < (unsigned)Ww);
        idx[n]  = min(max(yy, 0), Hh - 1) * Ww + min(max(xx, 0), Ww - 1);
        valf[n] = ok ? 1.f : 0.f;
    }

    const size_t base = (size_t)b * HW * 256 + slot * 8;
    const f16x8 q8 = *(const f16x8*)(qryT + base + (size_t)p * 256);

    f16x2 qp[4];
    qp[0] = __builtin_shufflevector(q8, q8, 0, 1);
    qp[1] = __builtin_shufflevector(q8, q8, 2, 3);
    qp[2] = __builtin_shufflevector(q8, q8, 4, 5);
    qp[3] = __builtin_shufflevector(q8, q8, 6, 7);

    float sim[NB];
    #pragma unroll
    for (int n = 0; n < NB; ++n) {
        const f16x8 k8 = *(const f16x8*)(keyT + base + (size_t)idx[n] * 256);
        float s = 0.f;
        s = __builtin_amdgcn_fdot2(__builtin_shufflevector(k8, k8, 0, 1), qp[0], s, false);
        s = __builtin_amdgcn_fdot2(__builtin_shufflevector(k8, k8, 2, 3), qp[1], s, false);
        s = __builtin_amdgcn_fdot2(__builtin_shufflevector(k8, k8, 4, 5), qp[2], s, false);
        s = __builtin_amdgcn_fdot2(__builtin_shufflevector(k8, k8, 6, 7), qp[3], s, false);
        sim[n] = s;
    }

    #pragma unroll
    for (int n = 0; n < NB; ++n) {
        float s = sim[n];
        s += __shfl_xor(s, 1);
        s += __shfl_xor(s, 2);
        s += __shfl_xor(s, 4);
        s += __shfl_xor(s, 8);
        s += __shfl_xor(s, 16);
        sim[n] = s * valf[n];
    }

    float mx = sim[0];
    #pragma unroll
    for (int n = 1; n < NB; ++n) mx = fmaxf(mx, sim[n]);
    float sum = 0.f;
    #pragma unroll
    for (int n = 0; n < NB; ++n) { sim[n] = __expf(sim[n] - mx); sum += sim[n]; }
    const float inv = 1.f / sum;
    #pragma unroll
    for (int n = 0; n < NB; ++n) sim[n] = sim[n] * inv * valf[n];

    float acc[8];
    #pragma unroll
    for (int i = 0; i < 8; ++i) acc[i] = 0.f;
    #pragma unroll
    for (int n = 0; n < NB; ++n) {
        const f16x8 v8 = *(const f16x8*)(valT + base + (size_t)idx[n] * 256);
        const float w = sim[n];
        #pragma unroll
        for (int i = 0; i < 8; ++i) acc[i] = fmaf(w, (float)v8[i], acc[i]);
    }

    f16x8 h;
    #pragma unroll
    for (int i = 0; i < 8; ++i) h[i] = (_Float16)acc[i];
    *(f16x8*)(ctxT + base + (size_t)p * 256) = h;
}

extern "C" void kernel_launch(void* const* d_in, const int* in_sizes, int n_in,
                              void* d_out, int out_size, void* d_ws, size_t ws_size,
                              hipStream_t stream)
{
    (void)in_sizes; (void)n_in; (void)out_size; (void)ws_size;
    const float* x     = (const float*)d_in[0];
    const float* k1_w  = (const float*)d_in[1];
    const float* k1_b  = (const float*)d_in[2];
    const float* k1_g  = (const float*)d_in[3];
    const float* k1_be = (const float*)d_in[4];
    const float* k1_m  = (const float*)d_in[5];
    const float* k1_v  = (const float*)d_in[6];
    const float* k2_w  = (const float*)d_in[7];
    const float* k2_b  = (const float*)d_in[8];
    const float* k2_g  = (const float*)d_in[9];
    const float* k2_be = (const float*)d_in[10];
    const float* k2_m  = (const float*)d_in[11];
    const float* k2_v  = (const float*)d_in[12];
    const float* q1_w  = (const float*)d_in[13];
    const float* q1_b  = (const float*)d_in[14];
    const float* q1_g  = (const float*)d_in[15];
    const float* q1_be = (const float*)d_in[16];
    const float* q1_m  = (const float*)d_in[17];
    const float* q1_v  = (const float*)d_in[18];
    const float* q2_w  = (const float*)d_in[19];
    const float* q2_b  = (const float*)d_in[20];
    const float* q2_g  = (const float*)d_in[21];
    const float* q2_be = (const float*)d_in[22];
    const float* q2_m  = (const float*)d_in[23];
    const float* q2_v  = (const float*)d_in[24];
    const float* v_w   = (const float*)d_in[25];
    const float* v_b   = (const float*)d_in[26];
    const float* w_w   = (const float*)d_in[27];
    const float* w_b   = (const float*)d_in[28];

    _Float16* hw = (_Float16*)d_ws;
    const size_t SH = (size_t)4 * HW * 256;
    _Float16* wv_h  = hw;
    _Float16* wk1_h = wv_h  + 131072;
    _Float16* wq1_h = wk1_h + 131072;
    _Float16* wk2_h = wq1_h + 131072;
    _Float16* wq2_h = wk2_h + 65536;
    _Float16* ww_h  = wq2_h + 65536;
    _Float16* k1T   = ww_h  + 131072;
    _Float16* q1T   = k1T + SH;
    _Float16* valT  = q1T + SH;
    _Float16* ctxT  = valT + SH;
    _Float16* keyPC = ctxT + SH;
    _Float16* qryPC = keyPC + SH;

    prep_kernel<<<384, 256, 0, stream>>>(v_w, k1_w, q1_w, k2_w, q2_w, w_w,
                                         wv_h, wk1_h, wq1_h, wk2_h, wq2_h, ww_h);

    GJob jv  = { nullptr, x, wv_h,  v_b,  nullptr, nullptr, nullptr, nullptr, valT,  nullptr };
    GJob jk1 = { nullptr, x, wk1_h, k1_b, k1_g, k1_be, k1_m, k1_v,            k1T,   nullptr };
    GJob jq1 = { nullptr, x, wq1_h, q1_b, q1_g, q1_be, q1_m, q1_v,            q1T,   nullptr };
    GJob jk2 = { k1T, nullptr, wk2_h, k2_b, k2_g, k2_be, k2_m, k2_v,          keyPC, nullptr };
    GJob jq2 = { q1T, nullptr, wq2_h, q2_b, q2_g, q2_be, q2_m, q2_v,          qryPC, nullptr };
    GJob jw  = { ctxT, nullptr, ww_h, w_b,  nullptr, nullptr, nullptr, nullptr, nullptr, (float*)d_out };

    // stage 1: {v,k1,q1} share staged B (f32 x direct); 512 blocks x 512 thr
    gemm_f<<<512, 512, 0, stream>>>(jv, jk1, jq1, 1, 512, 256, 0);
    // stage 2: k2 | q2, two 64-row A-tiles share B per block
    gemm_f<<<512, 512, 0, stream>>>(jk2, jq2, jq2, 2, 256, 256, 0);
    // stage 3: fused sim+softmax+PV -> ctxT (p,c) f16
    attn_fused<<<dim3(512, 4), 256, 0, stream>>>(keyPC, qryPC, valT, ctxT);
    // stage 4: final conv, out f32 (b,c,p) -> d_out
    gemm_f<<<512, 512, 0, stream>>>(jw, jw, jw, 4, 256, 512, 2);
}